// Round 6
// baseline (311875.049 us; speedup 1.0000x reference)
//
#include <hip/hip_runtime.h>

#define NSTATE 16
#define H1 75
#define CHUNK 256
#define NPROD 960  // threads in waves 1..15

// Round 6: (1) weights cached (W1/b1/b2 in LDS, per-lane W2 column in 75
// VGPRs — j = tid&15 is invariant for prologue/producer strides), (2) serial
// pair-min via DPP quad_perm instead of ds_bpermute, (3) hist padded to
// stride 9 (consumer bank conflicts). Arithmetic bit-identical to round 5:
// same IEEE f32 ops in same order, only operand routing changed.
__device__ __forceinline__ float dpp_xor1(float x) {
  // quad_perm [1,0,3,2] => partner lane within each aligned pair
  int i = __builtin_amdgcn_mov_dpp(__float_as_int(x), 0xB1, 0xF, 0xF, true);
  return __int_as_float(i);
}

__launch_bounds__(1024, 1)
__global__ void viterbi_lane2(const float* __restrict__ rx,
                              const float* __restrict__ W1,
                              const float* __restrict__ b1,
                              const float* __restrict__ W2,
                              const float* __restrict__ b2,
                              float* __restrict__ out, int T) {
  __shared__ float q_lds[2][CHUNK][NSTATE];  // 32 KB priors, double-buffered
  __shared__ float hist[2][CHUNK][9];        // pre-update u[0..7], pad->9 banks
  __shared__ float w1_lds[80], b1_lds[80], b2_lds[16];
  const int tid = (int)threadIdx.x;
  const int lane = tid & 63;
  const int j = tid & 15;  // invariant output column for this thread
  const int nchunks = (T + CHUNK - 1) / CHUNK;

  // ---- stage weights: W1/b1/b2 -> LDS, W2 column j -> registers ----
  if (tid < 80) {
    w1_lds[tid] = (tid < H1) ? W1[tid] : 0.f;
    b1_lds[tid] = (tid < H1) ? b1[tid] : 0.f;
  }
  if (tid < 16) b2_lds[tid] = b2[tid];
  float w2r[H1];
#pragma unroll
  for (int k = 0; k < H1; ++k) w2r[k] = W2[k * NSTATE + j];
  __syncthreads();
  const float b2j = b2_lds[j];

  // exact numpy-f32 prior for one (t, j): mul+add (NOT fma) for layer 1,
  // sequential-k FMA for layer 2, + b2 last.
#define PRIOR_ONE(rxv, dst)                                   \
  {                                                           \
    float acc = 0.f;                                          \
    _Pragma("unroll")                                         \
    for (int k = 0; k < H1; ++k) {                            \
      float h = __fadd_rn(__fmul_rn((rxv), w1_lds[k]), b1_lds[k]); \
      h = fmaxf(h, 0.f);                                      \
      acc = __fmaf_rn(h, w2r[k], acc);                        \
    }                                                         \
    (dst) = __fadd_rn(acc, b2j);                              \
  }

  // ---- prologue: priors for chunk 0 (all 1024 threads) ----
  {
    const int n0 = min(CHUNK, T);
    for (int id = tid; id < n0 * NSTATE; id += 1024) {
      const int tl = id >> 4;
      const float rxv = rx[tl];
      PRIOR_ONE(rxv, q_lds[0][tl][j]);
    }
  }
  __syncthreads();

  // lane-parallel state: lane holds w[j16] = u[j16 & 7], j16 = lane & 15.
  const int perm_src = (lane & 48) | ((2 * (lane & 15)) & 15);
  float w = 0.f;

  for (int c = 0; c < nchunks; ++c) {
    const int p = c & 1;
    const int base = c * CHUNK;
    const int nsteps = min(CHUNK, T - base);

    if (tid < 64) {
      // ---- serial ACS on chunk c ----
      for (int tl = 0; tl < nsteps; ++tl) {
        if (lane < 8) hist[p][tl][lane] = w;   // pre-update u[0..7]
        const float qv = q_lds[p][tl][lane & 15];
        const float v = __fsub_rn(w, qv);      // v[j] = u[j&7] - prior[j]
        const float vp = dpp_xor1(v);          // partner transition (lane^1)
        const float m = fminf(v, vp);          // even lanes: min(v[2i],v[2i+1])
        w = __shfl(m, perm_src);               // w'[j] = u'[j&7] = m[(2j)&15]
      }
    } else {
      // ---- producers: priors for chunk c+1 ----
      const int nc = c + 1;
      if (nc < nchunks) {
        const int nbase = nc * CHUNK;
        const int nn = min(CHUNK, T - nbase);
        for (int id = tid - 64; id < nn * NSTATE; id += NPROD) {
          const int tl = id >> 4;
          const float rxv = rx[nbase + tl];
          PRIOR_ONE(rxv, q_lds[1 - p][tl][j]);
        }
      }
      // ---- consumers: bits for chunk c-1 (strict-< first argmin) ----
      if (c > 0) {
        const int tl = tid - 64;
        if (tl < CHUNK) {
          const float* h = hist[1 - p][tl];
          float m = h[0]; int arg = 0;
          if (h[1] < m) { m = h[1]; arg = 1; }
          if (h[2] < m) { m = h[2]; arg = 2; }
          if (h[3] < m) { m = h[3]; arg = 3; }
          if (h[4] < m) { m = h[4]; arg = 4; }
          if (h[5] < m) { m = h[5]; arg = 5; }
          if (h[6] < m) { m = h[6]; arg = 6; }
          if (h[7] < m) { m = h[7]; arg = 7; }
          out[(c - 1) * CHUNK + tl] = (float)(arg & 1);
        }
      }
    }
    __syncthreads();
  }

  // ---- epilogue: bits for the last chunk ----
  {
    const int c = nchunks - 1;
    const int p = c & 1;
    const int base = c * CHUNK;
    const int nsteps = T - base;
    if (tid < nsteps) {
      const float* h = hist[p][tid];
      float m = h[0]; int arg = 0;
      if (h[1] < m) { m = h[1]; arg = 1; }
      if (h[2] < m) { m = h[2]; arg = 2; }
      if (h[3] < m) { m = h[3]; arg = 3; }
      if (h[4] < m) { m = h[4]; arg = 4; }
      if (h[5] < m) { m = h[5]; arg = 5; }
      if (h[6] < m) { m = h[6]; arg = 6; }
      if (h[7] < m) { m = h[7]; arg = 7; }
      out[base + tid] = (float)(arg & 1);
    }
  }
#undef PRIOR_ONE
}

extern "C" void kernel_launch(void* const* d_in, const int* in_sizes, int n_in,
                              void* d_out, int out_size, void* d_ws, size_t ws_size,
                              hipStream_t stream) {
  const float* rx = (const float*)d_in[0];
  const float* W1 = (const float*)d_in[1];
  const float* b1 = (const float*)d_in[2];
  const float* W2 = (const float*)d_in[3];
  const float* b2 = (const float*)d_in[4];
  float* out = (float*)d_out;
  const int T = in_sizes[0];
  viterbi_lane2<<<1, 1024, 0, stream>>>(rx, W1, b1, W2, b2, out, T);
}

// Round 7
// 270214.111 us; speedup vs baseline: 1.1542x; 1.1542x over previous
//
#include <hip/hip_runtime.h>

#define NSTATE 16
#define H1 75
#define CHUNK 256
#define NPROD 960  // threads in waves 1..15

// Round 7: round-6 minus the scratch-spill bug (W2 lives in LDS, not 75
// VGPRs/thread — the spill caused 548 MB/dispatch of scratch traffic).
// Serial chain shortened to sub -> {2 parallel bpermutes} -> min (~38 cy).
// Arithmetic bit-identical to passing rounds 2/4/5: same IEEE f32 ops in the
// same order (fminf(v[2i], v[2i+1]) operand order preserved; zero-sign
// differences provably cannot flip any comparison).
__launch_bounds__(1024, 1)
__global__ void viterbi_lane3(const float* __restrict__ rx,
                              const float* __restrict__ W1,
                              const float* __restrict__ b1,
                              const float* __restrict__ W2,
                              const float* __restrict__ b2,
                              float* __restrict__ out, int T) {
  __shared__ float q_lds[2][CHUNK][NSTATE];  // 32 KB priors, double-buffered
  __shared__ float hist[2][CHUNK][9];        // pre-update u[0..7], pad->9 banks
  __shared__ float2 w1b1[H1];                // (W1[k], b1[k]) broadcast pairs
  __shared__ float w2_lds[H1][16];           // bank-conflict-free: bank=j+16(k&1)
  __shared__ float b2_lds[16];
  const int tid = (int)threadIdx.x;
  const int lane = tid & 63;
  const int j = tid & 15;  // invariant output column (strides 1024/960 ≡ 0 mod 16)
  const int nchunks = (T + CHUNK - 1) / CHUNK;

  // ---- stage weights into LDS ----
  if (tid < H1) w1b1[tid] = make_float2(W1[tid], b1[tid]);
  for (int i = tid; i < H1 * 16; i += 1024) w2_lds[i >> 4][i & 15] = W2[i];
  if (tid < 16) b2_lds[tid] = b2[tid];
  __syncthreads();
  const float b2j = b2_lds[j];

  // exact numpy-f32 prior for one (t, j): mul+add (NOT fma) for layer 1,
  // sequential-k FMA for layer 2, + b2 last.
#define PRIOR_ONE(rxv, dst)                                        \
  {                                                                \
    float acc = 0.f;                                               \
    _Pragma("unroll")                                              \
    for (int k = 0; k < H1; ++k) {                                 \
      const float2 wb = w1b1[k];                                   \
      float h = __fadd_rn(__fmul_rn((rxv), wb.x), wb.y);           \
      h = fmaxf(h, 0.f);                                           \
      acc = __fmaf_rn(h, w2_lds[k][j], acc);                       \
    }                                                              \
    (dst) = __fadd_rn(acc, b2j);                                   \
  }

  // ---- prologue: priors for chunk 0 (all 1024 threads) ----
  {
    const int n0 = min(CHUNK, T);
    for (int id = tid; id < n0 * NSTATE; id += 1024) {
      const int tl = id >> 4;
      const float rxv = rx[tl];
      PRIOR_ONE(rxv, q_lds[0][tl][j]);
    }
  }
  __syncthreads();

  // lane-parallel state: lane holds w[j16] = u[j16 & 7], j16 = lane & 15.
  // step: v[j] = w[j] - q[j]; w'[j] = fminf(v[(2j)&15], v[(2j)&15 + 1]).
  const int srcA = (lane & 48) | ((2 * (lane & 15)) & 15);  // even
  const int srcB = srcA + 1;
  float w = 0.f;

  for (int c = 0; c < nchunks; ++c) {
    const int p = c & 1;
    const int base = c * CHUNK;
    const int nsteps = min(CHUNK, T - base);

    if (tid < 64) {
      // ---- serial ACS on chunk c ----
#pragma unroll 4
      for (int tl = 0; tl < nsteps; ++tl) {
        if (lane < 8) hist[p][tl][lane] = w;   // pre-update u[0..7]
        const float qv = q_lds[p][tl][lane & 15];
        const float v = __fsub_rn(w, qv);      // v[j] = u[j&7] - prior[j]
        const float wa = __shfl(v, srcA);      // v[2i]   (first min operand)
        const float wb = __shfl(v, srcB);      // v[2i+1] (second)
        w = fminf(wa, wb);                     // u'[j&7]
      }
    } else {
      // ---- producers: priors for chunk c+1 ----
      const int nc = c + 1;
      if (nc < nchunks) {
        const int nbase = nc * CHUNK;
        const int nn = min(CHUNK, T - nbase);
        for (int id = tid - 64; id < nn * NSTATE; id += NPROD) {
          const int tl = id >> 4;
          const float rxv = rx[nbase + tl];
          PRIOR_ONE(rxv, q_lds[1 - p][tl][j]);
        }
      }
      // ---- consumers: bits for chunk c-1 (strict-< first argmin) ----
      if (c > 0) {
        const int tl = tid - 64;
        if (tl < CHUNK) {
          const float* h = hist[1 - p][tl];
          float m = h[0]; int arg = 0;
          if (h[1] < m) { m = h[1]; arg = 1; }
          if (h[2] < m) { m = h[2]; arg = 2; }
          if (h[3] < m) { m = h[3]; arg = 3; }
          if (h[4] < m) { m = h[4]; arg = 4; }
          if (h[5] < m) { m = h[5]; arg = 5; }
          if (h[6] < m) { m = h[6]; arg = 6; }
          if (h[7] < m) { m = h[7]; arg = 7; }
          out[(c - 1) * CHUNK + tl] = (float)(arg & 1);
        }
      }
    }
    __syncthreads();
  }

  // ---- epilogue: bits for the last chunk ----
  {
    const int c = nchunks - 1;
    const int p = c & 1;
    const int base = c * CHUNK;
    const int nsteps = T - base;
    if (tid < nsteps) {
      const float* h = hist[p][tid];
      float m = h[0]; int arg = 0;
      if (h[1] < m) { m = h[1]; arg = 1; }
      if (h[2] < m) { m = h[2]; arg = 2; }
      if (h[3] < m) { m = h[3]; arg = 3; }
      if (h[4] < m) { m = h[4]; arg = 4; }
      if (h[5] < m) { m = h[5]; arg = 5; }
      if (h[6] < m) { m = h[6]; arg = 6; }
      if (h[7] < m) { m = h[7]; arg = 7; }
      out[base + tid] = (float)(arg & 1);
    }
  }
#undef PRIOR_ONE
}

extern "C" void kernel_launch(void* const* d_in, const int* in_sizes, int n_in,
                              void* d_out, int out_size, void* d_ws, size_t ws_size,
                              hipStream_t stream) {
  const float* rx = (const float*)d_in[0];
  const float* W1 = (const float*)d_in[1];
  const float* b1 = (const float*)d_in[2];
  const float* W2 = (const float*)d_in[3];
  const float* b2 = (const float*)d_in[4];
  float* out = (float*)d_out;
  const int T = in_sizes[0];
  viterbi_lane3<<<1, 1024, 0, stream>>>(rx, W1, b1, W2, b2, out, T);
}

// Round 8
// 19860.356 us; speedup vs baseline: 15.7034x; 13.6057x over previous
//
#include <hip/hip_runtime.h>

#define NSTATE 16
#define H1 75
#define CHUNK 252   // divisible by 3 (butterfly phase period)
#define NPROD 960

// Round 8: serial ACS as a 3-phase de Bruijn butterfly entirely in DPP ops
// (no LDS in the dependent chain). Storage S_t[i] = u[rotr3^t(i)], states on
// lane bits (b0,b1,b3); step t xors storage bit (t%3): lane^1 (quad_perm
// 0xB1), lane^2 (quad_perm 0x4E), lane^8 (row_ror:8 0x128). q-pair is one
// prefetched ds_read_b64; hist dump predicated, off-chain. Producers read
// weights from GLOBAL (round-5 form) — LDS pipe stays quiet (rounds 6/7
// regression was producer DS flood poisoning the serial chain's DS waits).
// Arithmetic bit-identical: same IEEE f32 ops, same order, same fminf
// operand order; only data routing changed.
#define DPP_SWAP(x, CTRL) \
  __int_as_float(__builtin_amdgcn_mov_dpp(__float_as_int(x), (CTRL), 0xF, 0xF, true))

__launch_bounds__(1024, 1)
__global__ void viterbi_bfly(const float* __restrict__ rx,
                             const float* __restrict__ W1,
                             const float* __restrict__ b1,
                             const float* __restrict__ W2,
                             const float* __restrict__ b2,
                             float* __restrict__ out, int T) {
  __shared__ float q_lds[2][CHUNK][NSTATE];  // 31.5 KB priors, double-buffered
  __shared__ float hist[2][CHUNK][9];        // 17.7 KB pre-update u[0..7], pad 9
  const int tid = (int)threadIdx.x;
  const int lane = tid & 63;
  const int j = tid & 15;  // producer column (strides 1024/960 ≡ 0 mod 16)
  const int nchunks = (T + CHUNK - 1) / CHUNK;

  // exact numpy-f32 prior: mul+add (NOT fma) layer 1, sequential-k FMA layer 2.
#define PRIOR_ONE(rxv, dst)                                   \
  {                                                           \
    float acc = 0.f;                                          \
    for (int k = 0; k < H1; ++k) {                            \
      float h = __fadd_rn(__fmul_rn((rxv), W1[k]), b1[k]);    \
      h = fmaxf(h, 0.f);                                      \
      acc = __fmaf_rn(h, W2[k * NSTATE + j], acc);            \
    }                                                         \
    (dst) = __fadd_rn(acc, b2[j]);                            \
  }

  // ---- prologue: priors for chunk 0 ----
  {
    const int n0 = min(CHUNK, T);
    for (int id = tid; id < n0 * NSTATE; id += 1024) {
      const int tl = id >> 4;
      const float rxv = rx[tl];
      PRIOR_ONE(rxv, q_lds[0][tl][j]);
    }
  }
  __syncthreads();

  // ---- per-lane butterfly constants ----
  // storage index i on lane bits (b0, b1, b3); bit2/4/5 are replicas.
  const int i3 = (lane & 3) | ((lane >> 1) & 4);
  const int rotr_i = ((i3 >> 1) | (i3 << 2)) & 7;
  const int rotl_i = ((i3 << 1) | (i3 >> 2)) & 7;
  // phase ph: new state s_ph = rotr^{ph+1}(i)
  const int s0 = rotr_i, s1 = rotl_i, s2 = i3;
  const int q0 = 2 * s0, q1 = 2 * s1, q2 = 2 * s2;   // q float index of edge pair
  const bool r0 = (s0 & 4) != 0, r1 = (s1 & 4) != 0, r2 = (s2 & 4) != 0;
  // pre-update state held by this lane at phase ph: rotr^{ph}(i)
  const int d0 = i3, d1 = rotr_i, d2 = rotl_i;
  const bool dumper = (lane < 16) && ((lane & 4) == 0);  // lanes cover i=0..7

  float w = 0.f;  // S[i] = u[i] at phase 0 (chunk boundaries are phase-aligned)

  for (int c = 0; c < nchunks; ++c) {
    const int p = c & 1;
    const int base = c * CHUNK;
    const int nsteps = min(CHUNK, T - base);
    const int npad = ((nsteps + 2) / 3) * 3;  // pad to triple; pad rows unused

    if (tid < 64) {
      // ---- serial ACS, 3-phase butterfly, q prefetched one triple ahead ----
      const float* qb = &q_lds[p][0][0];
      float2 f0 = *(const float2*)(qb + 0 * 16 + q0);
      float2 f1 = *(const float2*)(qb + 1 * 16 + q1);
      float2 f2 = *(const float2*)(qb + 2 * 16 + q2);
      for (int tl = 0; tl < npad; tl += 3) {
        const int nt = min(tl + 3, CHUNK - 3);  // clamp: in-bounds, maybe garbage
        float2 g0 = *(const float2*)(qb + (nt + 0) * 16 + q0);
        float2 g1 = *(const float2*)(qb + (nt + 1) * 16 + q1);
        float2 g2 = *(const float2*)(qb + (nt + 2) * 16 + q2);
        // phase 0: partner = storage bit0 = lane^1
        if (dumper) hist[p][tl][d0] = w;
        {
          const float wp = DPP_SWAP(w, 0xB1);
          const float we = r0 ? wp : w, wo = r0 ? w : wp;
          w = fminf(__fsub_rn(we, f0.x), __fsub_rn(wo, f0.y));
        }
        // phase 1: partner = storage bit1 = lane^2
        if (dumper) hist[p][tl + 1][d1] = w;
        {
          const float wp = DPP_SWAP(w, 0x4E);
          const float we = r1 ? wp : w, wo = r1 ? w : wp;
          w = fminf(__fsub_rn(we, f1.x), __fsub_rn(wo, f1.y));
        }
        // phase 2: partner = storage bit2 = lane^8 (row_ror:8)
        if (dumper) hist[p][tl + 2][d2] = w;
        {
          const float wp = DPP_SWAP(w, 0x128);
          const float we = r2 ? wp : w, wo = r2 ? w : wp;
          w = fminf(__fsub_rn(we, f2.x), __fsub_rn(wo, f2.y));
        }
        f0 = g0; f1 = g1; f2 = g2;
      }
    } else {
      // ---- producers: priors for chunk c+1 (global weight reads) ----
      const int nc = c + 1;
      if (nc < nchunks) {
        const int nbase = nc * CHUNK;
        const int nn = min(CHUNK, T - nbase);
        for (int id = tid - 64; id < nn * NSTATE; id += NPROD) {
          const int tl = id >> 4;
          const float rxv = rx[nbase + tl];
          PRIOR_ONE(rxv, q_lds[1 - p][tl][j]);
        }
      }
      // ---- consumers: bits for chunk c-1 (strict-< first argmin) ----
      if (c > 0) {
        const int tl = tid - 64;
        if (tl < CHUNK) {
          const float* h = hist[1 - p][tl];
          float m = h[0]; int arg = 0;
          if (h[1] < m) { m = h[1]; arg = 1; }
          if (h[2] < m) { m = h[2]; arg = 2; }
          if (h[3] < m) { m = h[3]; arg = 3; }
          if (h[4] < m) { m = h[4]; arg = 4; }
          if (h[5] < m) { m = h[5]; arg = 5; }
          if (h[6] < m) { m = h[6]; arg = 6; }
          if (h[7] < m) { m = h[7]; arg = 7; }
          out[(c - 1) * CHUNK + tl] = (float)(arg & 1);
        }
      }
    }
    __syncthreads();
  }

  // ---- epilogue: bits for the last chunk ----
  {
    const int c = nchunks - 1;
    const int p = c & 1;
    const int base = c * CHUNK;
    const int nsteps = T - base;
    if (tid < nsteps) {
      const float* h = hist[p][tid];
      float m = h[0]; int arg = 0;
      if (h[1] < m) { m = h[1]; arg = 1; }
      if (h[2] < m) { m = h[2]; arg = 2; }
      if (h[3] < m) { m = h[3]; arg = 3; }
      if (h[4] < m) { m = h[4]; arg = 4; }
      if (h[5] < m) { m = h[5]; arg = 5; }
      if (h[6] < m) { m = h[6]; arg = 6; }
      if (h[7] < m) { m = h[7]; arg = 7; }
      out[base + tid] = (float)(arg & 1);
    }
  }
#undef PRIOR_ONE
}

extern "C" void kernel_launch(void* const* d_in, const int* in_sizes, int n_in,
                              void* d_out, int out_size, void* d_ws, size_t ws_size,
                              hipStream_t stream) {
  const float* rx = (const float*)d_in[0];
  const float* W1 = (const float*)d_in[1];
  const float* b1 = (const float*)d_in[2];
  const float* W2 = (const float*)d_in[3];
  const float* b2 = (const float*)d_in[4];
  float* out = (float*)d_out;
  const int T = in_sizes[0];
  viterbi_bfly<<<1, 1024, 0, stream>>>(rx, W1, b1, W2, b2, out, T);
}